// Round 3
// baseline (1950.834 us; speedup 1.0000x reference)
//
#include <hip/hip_runtime.h>

#define GAMMA_C 5.0f
#define COST_C 1e-3f
#define ITERS_C 200
#define ETA0_C 0.02f
#define B_C 128
#define H_C 12
#define N_C 128
#define HPB 6    // time steps per block (block pair covers 12)
#define RRF 88   // Sigma rows 0..RRF-1 in registers (1 float per lane-column)
#define RLF 40   // Sigma rows RRF..127 in LDS

__device__ __forceinline__ float sgnf(float x) {
    return (x > 0.f) ? 1.f : ((x < 0.f) ? -1.f : 0.f);
}
__device__ __forceinline__ float rdlane(float v, int l) {
    return __int_as_float(__builtin_amdgcn_readlane(__float_as_int(v), l));
}

// ---------------- Sigma[b,h] = L[b,h] @ L[b,h]^T ----------------
__global__ __launch_bounds__(256) void sigma_kernel(const float* __restrict__ L,
                                                    float* __restrict__ Sigma) {
    __shared__ float Ls[N_C][N_C + 1];
    const size_t base = (size_t)blockIdx.x * (N_C * N_C);
    const float* Lbh = L + base;
    for (int idx = threadIdx.x; idx < N_C * N_C; idx += 256) {
        Ls[idx >> 7][idx & 127] = Lbh[idx];
    }
    __syncthreads();
    const int ti = threadIdx.x >> 4, tj = threadIdx.x & 15;
    const int i0 = ti * 8, j0 = tj * 8;
    float acc[8][8];
#pragma unroll
    for (int x = 0; x < 8; ++x)
#pragma unroll
        for (int y = 0; y < 8; ++y) acc[x][y] = 0.f;
    for (int k = 0; k < N_C; ++k) {
        float a[8], bb[8];
#pragma unroll
        for (int d = 0; d < 8; ++d) {
            a[d] = Ls[i0 + d][k];
            bb[d] = Ls[j0 + d][k];
        }
#pragma unroll
        for (int x = 0; x < 8; ++x)
#pragma unroll
            for (int y = 0; y < 8; ++y) acc[x][y] = fmaf(a[x], bb[y], acc[x][y]);
    }
    float* Sbh = Sigma + base;
#pragma unroll
    for (int x = 0; x < 8; ++x)
#pragma unroll
        for (int y = 0; y < 8; ++y) Sbh[(size_t)(i0 + x) * N_C + (j0 + y)] = acc[x][y];
}

__global__ void init_flags(int* __restrict__ flags) {
    if (threadIdx.x < 2 * B_C) flags[threadIdx.x] = 0;
}

// ---------------- Resident iterate kernel v2 (spill-free) ----------------
// 256 blocks x 768 threads (12 waves). Block pair per batch: half 0 = h0-5,
// half 1 = h6-11. Wave pair (2 waves) per h; lane owns ONE column c=sub*64+lane.
// Sigma rows 0..RRF-1 in VGPRs (88 floats/lane), RRF..127 in LDS.
// Phase 1: z = Sigma w (readlane broadcast) + gradient -> v in LDS. barrier.
// Phase 2: both waves of the pair redundantly project all 128 cols (2/lane,
// wave-local Michelot); sub==0 writes new w. barrier.
// h5<->h6 coupling via double-buffered global slot + agent-scope flag sync
// (pair bids n, n+8 -> same XCD round-robin; 256 blocks <= 256 CUs co-resident).
__global__ __launch_bounds__(768, 3) void mpo_resident2(
    const float* __restrict__ mu, const float* __restrict__ Sigma,
    const float* __restrict__ w_prev, float* __restrict__ out,
    float* __restrict__ wx, int* __restrict__ flags) {
    const int bid = blockIdx.x;
    const int b = (bid >> 4) * 8 + (bid & 7);  // batch 0..127
    const int half = (bid >> 3) & 1;           // 0: h0-5, 1: h6-11
    const int wv = threadIdx.x >> 6;           // wave 0..11
    const int lane = threadIdx.x & 63;
    const int hl = wv >> 1;                    // local h 0..5
    const int sub = wv & 1;                    // column half
    const int h = half * HPB + hl;
    const int c = sub * 64 + lane;             // this lane's matvec column

    __shared__ float slds[HPB][RLF][N_C];  // 122880 B
    __shared__ float wbuf[2][HPB][N_C];    //   6144 B
    __shared__ float vbuf[HPB][N_C];       //   3072 B
    __shared__ float wps[N_C];             //    512 B

    const float* Sbh = Sigma + (((size_t)b * H_C + h) << 14);

    // Rows 0..RRF-1 -> registers (1 float per lane), RRF..127 -> LDS. Coalesced.
    float sreg[RRF];
#pragma unroll
    for (int j = 0; j < RRF; ++j) sreg[j] = Sbh[j * N_C + c];
#pragma unroll
    for (int j = 0; j < RLF; ++j) slds[hl][j][c] = Sbh[(RRF + j) * N_C + c];

    const float muc = mu[((size_t)b * H_C + h) * N_C + c];
    if (threadIdx.x < N_C) wps[threadIdx.x] = w_prev[(size_t)b * N_C + threadIdx.x];
    if (wv < HPB) {
        wbuf[0][wv][lane] = 1.f / N_C;
        wbuf[0][wv][64 + lane] = 1.f / N_C;
    }

    float* wx_own = wx + (size_t)(b * 2 + half) * 2 * N_C;
    const float* wx_par = wx + (size_t)(b * 2 + (half ^ 1)) * 2 * N_C;
    int* flag_own = flags + b * 2 + half;
    int* flag_par = flags + b * 2 + (half ^ 1);
    const bool is_bndA = (half == 0 && hl == HPB - 1);  // h5: consumes w6
    const bool is_bndB = (half == 1 && hl == 0);        // h6: consumes w5
    const bool exporter = (sub == 0) && (is_bndA || is_bndB);

    __syncthreads();

    int p = 0;
    for (int k = 0; k < ITERS_C; ++k) {
        // ---- phase 1: z = Sigma w at column c ----
        const float wb0 = wbuf[p][hl][lane];       // w[lane]
        const float wb1 = wbuf[p][hl][64 + lane];  // w[64+lane]
        float z = 0.f;
#pragma unroll
        for (int j = 0; j < 64; ++j) z = fmaf(rdlane(wb0, j), sreg[j], z);
#pragma unroll
        for (int j = 64; j < RRF; ++j) z = fmaf(rdlane(wb1, j - 64), sreg[j], z);
#pragma unroll
        for (int j = RRF; j < N_C; ++j)
            z = fmaf(rdlane(wb1, j - 64), slds[hl][j - RRF][c], z);

        const float wc = sub ? wb1 : wb0;  // own w[c]

        // ---- neighbor signs ----
        float wm;
        if (hl > 0) {
            wm = wbuf[p][hl - 1][c];
        } else if (half == 0) {
            wm = wps[c];
        } else {  // h6 consumes w5
            if (k == 0) {
                wm = 1.f / N_C;
            } else {
                while (__hip_atomic_load(flag_par, __ATOMIC_ACQUIRE,
                                         __HIP_MEMORY_SCOPE_AGENT) < k)
                    __builtin_amdgcn_s_sleep(2);
                wm = __hip_atomic_load(wx_par + (size_t)(k & 1) * N_C + c,
                                       __ATOMIC_RELAXED, __HIP_MEMORY_SCOPE_AGENT);
            }
        }
        float sn = 0.f;
        if (hl < HPB - 1) {
            sn = sgnf(wbuf[p][hl + 1][c] - wc);
        } else if (half == 0) {  // h5 consumes w6
            float wn;
            if (k == 0) {
                wn = 1.f / N_C;
            } else {
                while (__hip_atomic_load(flag_par, __ATOMIC_ACQUIRE,
                                         __HIP_MEMORY_SCOPE_AGENT) < k)
                    __builtin_amdgcn_s_sleep(2);
                wn = __hip_atomic_load(wx_par + (size_t)(k & 1) * N_C + c,
                                       __ATOMIC_RELAXED, __HIP_MEMORY_SCOPE_AGENT);
            }
            sn = sgnf(wn - wc);
        }
        const float s = sgnf(wc - wm);

        const float eta = ETA0_C / sqrtf((float)(k + 1));
        vbuf[hl][c] = wc - eta * (-muc + 2.f * GAMMA_C * z + COST_C * (s - sn));
        __syncthreads();

        // ---- phase 2: redundant wave-local projection (2 cols/lane) ----
        const float2 vv = *(const float2*)&vbuf[hl][lane * 2];
        const float v0 = vv.x, v1 = vv.y;
        float a0 = 1.f, a1 = 1.f, theta = 0.f;
        for (int it = 0; it < N_C; ++it) {
            float sm = a0 * v0 + a1 * v1;
            float cn = a0 + a1;
#pragma unroll
            for (int d = 1; d < 64; d <<= 1) {
                sm += __shfl_xor(sm, d);
                cn += __shfl_xor(cn, d);
            }
            theta = (sm - 1.f) / cn;
            const float na0 = (v0 > theta) ? 1.f : 0.f;
            const float na1 = (v1 > theta) ? 1.f : 0.f;
            const bool changed = (na0 != a0) || (na1 != a1);
            a0 = na0;
            a1 = na1;
            if (!__any(changed)) break;
        }
        const float nw0 = fmaxf(v0 - theta, 0.f);
        const float nw1 = fmaxf(v1 - theta, 0.f);

        if (sub == 0) {
            wbuf[p ^ 1][hl][lane * 2] = nw0;
            wbuf[p ^ 1][hl][lane * 2 + 1] = nw1;
        }
        if (exporter) {
            float* dst = wx_own + (size_t)((k + 1) & 1) * N_C;
            __hip_atomic_store(dst + lane * 2, nw0, __ATOMIC_RELAXED,
                               __HIP_MEMORY_SCOPE_AGENT);
            __hip_atomic_store(dst + lane * 2 + 1, nw1, __ATOMIC_RELAXED,
                               __HIP_MEMORY_SCOPE_AGENT);
            // release: waits on this wave's prior stores before flag becomes visible
            __hip_atomic_store(flag_own, k + 1, __ATOMIC_RELEASE,
                               __HIP_MEMORY_SCOPE_AGENT);
        }
        __syncthreads();
        p ^= 1;
    }

    out[((size_t)b * H_C + h) * N_C + c] = wbuf[p][hl][c];
}

// ---------------- Streaming fallbacks (round-1 structure) ----------------
template <int USE_SIGMA>
__global__ __launch_bounds__(768) void mpo_iterate(const float* __restrict__ mu,
                                                   const float* __restrict__ M,
                                                   const float* __restrict__ w_prev,
                                                   float* __restrict__ out) {
    const int b = blockIdx.x;
    const int h = threadIdx.x >> 6;
    const int lane = threadIdx.x & 63;
    const int c0 = lane * 2, c1 = c0 + 1;

    __shared__ float wbuf[2][H_C][N_C];
    __shared__ float wps[N_C];
    __shared__ float zbuf[H_C][N_C];

    const size_t mbase = ((size_t)b * H_C + h) * (size_t)(N_C * N_C);
    const float* Mbh = M + mbase;
    const float mu0 = mu[((size_t)b * H_C + h) * N_C + c0];
    const float mu1 = mu[((size_t)b * H_C + h) * N_C + c1];

    if (threadIdx.x < N_C) wps[threadIdx.x] = w_prev[(size_t)b * N_C + threadIdx.x];
    wbuf[0][h][c0] = 1.f / N_C;
    wbuf[0][h][c1] = 1.f / N_C;
    __syncthreads();

    int p = 0;
    float nw0 = 1.f / N_C, nw1 = 1.f / N_C;

    for (int k = 0; k < ITERS_C; ++k) {
        const float* wrow = wbuf[p][h];
        float z0 = 0.f, z1 = 0.f;

        if (USE_SIGMA) {
#pragma unroll 8
            for (int j = 0; j < N_C; ++j) {
                const float wj = wrow[j];
                const float2 sv = *(const float2*)(Mbh + (size_t)j * N_C + c0);
                z0 = fmaf(wj, sv.x, z0);
                z1 = fmaf(wj, sv.y, z1);
            }
        } else {
            float y0 = 0.f, y1 = 0.f;
#pragma unroll 8
            for (int j = 0; j < N_C; ++j) {
                const float wj = wrow[j];
                const float2 lv = *(const float2*)(Mbh + (size_t)j * N_C + c0);
                y0 = fmaf(wj, lv.x, y0);
                y1 = fmaf(wj, lv.y, y1);
            }
            for (int i = 0; i < N_C; ++i) {
                const float2 lv = *(const float2*)(Mbh + (size_t)i * N_C + c0);
                float part = lv.x * y0 + lv.y * y1;
#pragma unroll
                for (int d = 1; d < 64; d <<= 1) part += __shfl_xor(part, d);
                if (lane == (i & 63)) zbuf[h][i] = part;
            }
            __syncthreads();
            z0 = zbuf[h][c0];
            z1 = zbuf[h][c1];
        }

        const float w0 = wrow[c0], w1 = wrow[c1];
        float wp0, wp1;
        if (h == 0) {
            wp0 = wps[c0];
            wp1 = wps[c1];
        } else {
            wp0 = wbuf[p][h - 1][c0];
            wp1 = wbuf[p][h - 1][c1];
        }
        const float s0 = sgnf(w0 - wp0), s1 = sgnf(w1 - wp1);
        float sn0 = 0.f, sn1 = 0.f;
        if (h < H_C - 1) {
            sn0 = sgnf(wbuf[p][h + 1][c0] - w0);
            sn1 = sgnf(wbuf[p][h + 1][c1] - w1);
        }
        const float eta = ETA0_C / sqrtf((float)(k + 1));
        const float g0 = -mu0 + 2.f * GAMMA_C * z0 + COST_C * (s0 - sn0);
        const float g1 = -mu1 + 2.f * GAMMA_C * z1 + COST_C * (s1 - sn1);
        const float v0 = w0 - eta * g0;
        const float v1 = w1 - eta * g1;

        float a0 = 1.f, a1 = 1.f, theta = 0.f;
        for (int it = 0; it < N_C; ++it) {
            float s = a0 * v0 + a1 * v1;
            float c = a0 + a1;
#pragma unroll
            for (int d = 1; d < 64; d <<= 1) {
                s += __shfl_xor(s, d);
                c += __shfl_xor(c, d);
            }
            theta = (s - 1.f) / c;
            const float na0 = (v0 > theta) ? 1.f : 0.f;
            const float na1 = (v1 > theta) ? 1.f : 0.f;
            const bool changed = (na0 != a0) || (na1 != a1);
            a0 = na0;
            a1 = na1;
            if (!__any(changed)) break;
        }
        nw0 = fmaxf(v0 - theta, 0.f);
        nw1 = fmaxf(v1 - theta, 0.f);
        wbuf[p ^ 1][h][c0] = nw0;
        wbuf[p ^ 1][h][c1] = nw1;
        __syncthreads();
        p ^= 1;
    }

    out[((size_t)b * H_C + h) * N_C + c0] = nw0;
    out[((size_t)b * H_C + h) * N_C + c1] = nw1;
}

extern "C" void kernel_launch(void* const* d_in, const int* in_sizes, int n_in,
                              void* d_out, int out_size, void* d_ws, size_t ws_size,
                              hipStream_t stream) {
    const float* mu = (const float*)d_in[0];
    const float* L = (const float*)d_in[1];
    const float* w_prev = (const float*)d_in[2];
    float* out = (float*)d_out;

    const size_t sigma_elems = (size_t)B_C * H_C * N_C * N_C;
    const size_t sigma_bytes = sigma_elems * sizeof(float);
    const size_t wx_elems = (size_t)B_C * 2 * 2 * N_C;
    const size_t need = sigma_bytes + (wx_elems + 2 * B_C) * sizeof(float);

    if (ws_size >= need && d_ws != nullptr) {
        float* Sigma = (float*)d_ws;
        float* wxp = Sigma + sigma_elems;
        int* flags = (int*)(wxp + wx_elems);
        init_flags<<<1, 256, 0, stream>>>(flags);
        sigma_kernel<<<B_C * H_C, 256, 0, stream>>>(L, Sigma);
        mpo_resident2<<<2 * B_C, 768, 0, stream>>>(mu, Sigma, w_prev, out, wxp, flags);
    } else if (ws_size >= sigma_bytes && d_ws != nullptr) {
        float* Sigma = (float*)d_ws;
        sigma_kernel<<<B_C * H_C, 256, 0, stream>>>(L, Sigma);
        mpo_iterate<1><<<B_C, 768, 0, stream>>>(mu, Sigma, w_prev, out);
    } else {
        mpo_iterate<0><<<B_C, 768, 0, stream>>>(mu, L, w_prev, out);
    }
}

// Round 7
// 1938.141 us; speedup vs baseline: 1.0065x; 1.0065x over previous
//
#include <hip/hip_runtime.h>

#define GAMMA_C 5.0f
#define COST_C 1e-3f
#define ITERS_C 200
#define ETA0_C 0.02f
#define B_C 128
#define H_C 12
#define N_C 128
#define HPB 6    // time steps per block (block pair covers 12)
#define RRF 80   // Sigma rows 0..RRF-1 in registers (1 float per lane-column)
#define RLF 48   // Sigma rows RRF..127 in LDS

__device__ __forceinline__ float sgnf(float x) {
    return (x > 0.f) ? 1.f : ((x < 0.f) ? -1.f : 0.f);
}
__device__ __forceinline__ float rdlane(float v, int l) {
    return __int_as_float(__builtin_amdgcn_readlane(__float_as_int(v), l));
}

// ---------------- Sigma[b,h] = L[b,h] @ L[b,h]^T ----------------
__global__ __launch_bounds__(256) void sigma_kernel(const float* __restrict__ L,
                                                    float* __restrict__ Sigma) {
    __shared__ float Ls[N_C][N_C + 1];
    const size_t base = (size_t)blockIdx.x * (N_C * N_C);
    const float* Lbh = L + base;
    for (int idx = threadIdx.x; idx < N_C * N_C; idx += 256) {
        Ls[idx >> 7][idx & 127] = Lbh[idx];
    }
    __syncthreads();
    const int ti = threadIdx.x >> 4, tj = threadIdx.x & 15;
    const int i0 = ti * 8, j0 = tj * 8;
    float acc[8][8];
#pragma unroll
    for (int x = 0; x < 8; ++x)
#pragma unroll
        for (int y = 0; y < 8; ++y) acc[x][y] = 0.f;
    for (int k = 0; k < N_C; ++k) {
        float a[8], bb[8];
#pragma unroll
        for (int d = 0; d < 8; ++d) {
            a[d] = Ls[i0 + d][k];
            bb[d] = Ls[j0 + d][k];
        }
#pragma unroll
        for (int x = 0; x < 8; ++x)
#pragma unroll
            for (int y = 0; y < 8; ++y) acc[x][y] = fmaf(a[x], bb[y], acc[x][y]);
    }
    float* Sbh = Sigma + base;
#pragma unroll
    for (int x = 0; x < 8; ++x)
#pragma unroll
        for (int y = 0; y < 8; ++y) Sbh[(size_t)(i0 + x) * N_C + (j0 + y)] = acc[x][y];
}

__global__ void init_flags(int* __restrict__ flags) {
    if (threadIdx.x < 2 * B_C) flags[threadIdx.x] = 0;
}

// ---------------- Resident iterate kernel v3 (spill-free target) ----------------
// 256 blocks x 768 threads (12 waves). Block pair per batch: half 0 = h0-5,
// half 1 = h6-11. Wave pair (2 waves) per h; lane owns ONE column c=sub*64+lane.
// Sigma rows 0..RRF-1 in VGPRs (80 floats/lane), RRF..127 in LDS (48 rows).
// LDS total 157184 B -> 1 block/CU; 12 waves/CU = 3/SIMD. launch_bounds(768,1)
// leaves the VGPR cap high (observed allocator heuristic: cap ~ 512/(2*minw)).
__global__ __launch_bounds__(768, 1) void mpo_resident3(
    const float* __restrict__ mu, const float* __restrict__ Sigma,
    const float* __restrict__ w_prev, float* __restrict__ out,
    float* __restrict__ wx, int* __restrict__ flags) {
    const int bid = blockIdx.x;
    const int b = (bid >> 4) * 8 + (bid & 7);  // batch 0..127
    const int half = (bid >> 3) & 1;           // 0: h0-5, 1: h6-11
    const int wv = threadIdx.x >> 6;           // wave 0..11
    const int lane = threadIdx.x & 63;
    const int hl = wv >> 1;                    // local h 0..5
    const int sub = wv & 1;                    // column half
    const int h = half * HPB + hl;
    const int c = sub * 64 + lane;             // this lane's matvec column

    __shared__ float slds[HPB][RLF][N_C];  // 147456 B
    __shared__ float wbuf[2][HPB][N_C];    //   6144 B
    __shared__ float vbuf[HPB][N_C];       //   3072 B
    __shared__ float wps[N_C];             //    512 B

    const float* Sbh = Sigma + (((size_t)b * H_C + h) << 14);

    // Rows 0..RRF-1 -> registers (1 float per lane), RRF..127 -> LDS. Coalesced.
    float sreg[RRF];
#pragma unroll
    for (int j = 0; j < RRF; ++j) sreg[j] = Sbh[j * N_C + c];
#pragma unroll
    for (int j = 0; j < RLF; ++j) slds[hl][j][c] = Sbh[(RRF + j) * N_C + c];

    const float muc = mu[((size_t)b * H_C + h) * N_C + c];
    if (threadIdx.x < N_C) wps[threadIdx.x] = w_prev[(size_t)b * N_C + threadIdx.x];
    if (wv < HPB) {
        wbuf[0][wv][lane] = 1.f / N_C;
        wbuf[0][wv][64 + lane] = 1.f / N_C;
    }

    float* wx_own = wx + (size_t)(b * 2 + half) * 2 * N_C;
    const float* wx_par = wx + (size_t)(b * 2 + (half ^ 1)) * 2 * N_C;
    int* flag_own = flags + b * 2 + half;
    int* flag_par = flags + b * 2 + (half ^ 1);
    const bool is_bndA = (half == 0 && hl == HPB - 1);  // h5: consumes w6
    const bool is_bndB = (half == 1 && hl == 0);        // h6: consumes w5
    const bool exporter = (sub == 0) && (is_bndA || is_bndB);

    __syncthreads();

    int p = 0;
    for (int k = 0; k < ITERS_C; ++k) {
        // ---- phase 1: z = Sigma w at column c (4-way ILP accumulators) ----
        const float wb0 = wbuf[p][hl][lane];       // w[lane]
        const float wb1 = wbuf[p][hl][64 + lane];  // w[64+lane]
        float a0 = 0.f, a1 = 0.f, a2 = 0.f, a3 = 0.f;
#pragma unroll
        for (int j = 0; j < 64; j += 4) {
            a0 = fmaf(rdlane(wb0, j + 0), sreg[j + 0], a0);
            a1 = fmaf(rdlane(wb0, j + 1), sreg[j + 1], a1);
            a2 = fmaf(rdlane(wb0, j + 2), sreg[j + 2], a2);
            a3 = fmaf(rdlane(wb0, j + 3), sreg[j + 3], a3);
        }
#pragma unroll
        for (int j = 64; j < RRF; j += 4) {
            a0 = fmaf(rdlane(wb1, j - 64), sreg[j + 0], a0);
            a1 = fmaf(rdlane(wb1, j - 63), sreg[j + 1], a1);
            a2 = fmaf(rdlane(wb1, j - 62), sreg[j + 2], a2);
            a3 = fmaf(rdlane(wb1, j - 61), sreg[j + 3], a3);
        }
#pragma unroll
        for (int j = RRF; j < N_C; j += 4) {
            a0 = fmaf(rdlane(wb1, j - 64), slds[hl][j - RRF + 0][c], a0);
            a1 = fmaf(rdlane(wb1, j - 63), slds[hl][j - RRF + 1][c], a1);
            a2 = fmaf(rdlane(wb1, j - 62), slds[hl][j - RRF + 2][c], a2);
            a3 = fmaf(rdlane(wb1, j - 61), slds[hl][j - RRF + 3][c], a3);
        }
        const float z = (a0 + a2) + (a1 + a3);

        const float wc = sub ? wb1 : wb0;  // own w[c]

        // ---- neighbor signs ----
        float wm;
        if (hl > 0) {
            wm = wbuf[p][hl - 1][c];
        } else if (half == 0) {
            wm = wps[c];
        } else {  // h6 consumes w5
            if (k == 0) {
                wm = 1.f / N_C;
            } else {
                while (__hip_atomic_load(flag_par, __ATOMIC_ACQUIRE,
                                         __HIP_MEMORY_SCOPE_AGENT) < k)
                    __builtin_amdgcn_s_sleep(2);
                wm = __hip_atomic_load(wx_par + (size_t)(k & 1) * N_C + c,
                                       __ATOMIC_RELAXED, __HIP_MEMORY_SCOPE_AGENT);
            }
        }
        float sn = 0.f;
        if (hl < HPB - 1) {
            sn = sgnf(wbuf[p][hl + 1][c] - wc);
        } else if (half == 0) {  // h5 consumes w6
            float wn;
            if (k == 0) {
                wn = 1.f / N_C;
            } else {
                while (__hip_atomic_load(flag_par, __ATOMIC_ACQUIRE,
                                         __HIP_MEMORY_SCOPE_AGENT) < k)
                    __builtin_amdgcn_s_sleep(2);
                wn = __hip_atomic_load(wx_par + (size_t)(k & 1) * N_C + c,
                                       __ATOMIC_RELAXED, __HIP_MEMORY_SCOPE_AGENT);
            }
            sn = sgnf(wn - wc);
        }
        const float s = sgnf(wc - wm);

        const float eta = ETA0_C / sqrtf((float)(k + 1));
        vbuf[hl][c] = wc - eta * (-muc + 2.f * GAMMA_C * z + COST_C * (s - sn));
        __syncthreads();

        // ---- phase 2: redundant wave-local projection (2 cols/lane) ----
        const float2 vv = *(const float2*)&vbuf[hl][lane * 2];
        const float v0 = vv.x, v1 = vv.y;
        float g0 = 1.f, g1 = 1.f, theta = 0.f;
        for (int it = 0; it < N_C; ++it) {
            float sm = g0 * v0 + g1 * v1;
            float cn = g0 + g1;
#pragma unroll
            for (int d = 1; d < 64; d <<= 1) {
                sm += __shfl_xor(sm, d);
                cn += __shfl_xor(cn, d);
            }
            theta = (sm - 1.f) / cn;
            const float n0 = (v0 > theta) ? 1.f : 0.f;
            const float n1 = (v1 > theta) ? 1.f : 0.f;
            const bool changed = (n0 != g0) || (n1 != g1);
            g0 = n0;
            g1 = n1;
            if (!__any(changed)) break;
        }
        const float nw0 = fmaxf(v0 - theta, 0.f);
        const float nw1 = fmaxf(v1 - theta, 0.f);

        if (sub == 0) {
            wbuf[p ^ 1][hl][lane * 2] = nw0;
            wbuf[p ^ 1][hl][lane * 2 + 1] = nw1;
        }
        if (exporter) {
            float* dst = wx_own + (size_t)((k + 1) & 1) * N_C;
            __hip_atomic_store(dst + lane * 2, nw0, __ATOMIC_RELAXED,
                               __HIP_MEMORY_SCOPE_AGENT);
            __hip_atomic_store(dst + lane * 2 + 1, nw1, __ATOMIC_RELAXED,
                               __HIP_MEMORY_SCOPE_AGENT);
            // per-lane release orders each lane's own data stores before its flag store
            __hip_atomic_store(flag_own, k + 1, __ATOMIC_RELEASE,
                               __HIP_MEMORY_SCOPE_AGENT);
        }
        __syncthreads();
        p ^= 1;
    }

    out[((size_t)b * H_C + h) * N_C + c] = wbuf[p][hl][c];
}

// ---------------- Streaming fallbacks (round-1 structure) ----------------
template <int USE_SIGMA>
__global__ __launch_bounds__(768) void mpo_iterate(const float* __restrict__ mu,
                                                   const float* __restrict__ M,
                                                   const float* __restrict__ w_prev,
                                                   float* __restrict__ out) {
    const int b = blockIdx.x;
    const int h = threadIdx.x >> 6;
    const int lane = threadIdx.x & 63;
    const int c0 = lane * 2, c1 = c0 + 1;

    __shared__ float wbuf[2][H_C][N_C];
    __shared__ float wps[N_C];
    __shared__ float zbuf[H_C][N_C];

    const size_t mbase = ((size_t)b * H_C + h) * (size_t)(N_C * N_C);
    const float* Mbh = M + mbase;
    const float mu0 = mu[((size_t)b * H_C + h) * N_C + c0];
    const float mu1 = mu[((size_t)b * H_C + h) * N_C + c1];

    if (threadIdx.x < N_C) wps[threadIdx.x] = w_prev[(size_t)b * N_C + threadIdx.x];
    wbuf[0][h][c0] = 1.f / N_C;
    wbuf[0][h][c1] = 1.f / N_C;
    __syncthreads();

    int p = 0;
    float nw0 = 1.f / N_C, nw1 = 1.f / N_C;

    for (int k = 0; k < ITERS_C; ++k) {
        const float* wrow = wbuf[p][h];
        float z0 = 0.f, z1 = 0.f;

        if (USE_SIGMA) {
#pragma unroll 8
            for (int j = 0; j < N_C; ++j) {
                const float wj = wrow[j];
                const float2 sv = *(const float2*)(Mbh + (size_t)j * N_C + c0);
                z0 = fmaf(wj, sv.x, z0);
                z1 = fmaf(wj, sv.y, z1);
            }
        } else {
            float y0 = 0.f, y1 = 0.f;
#pragma unroll 8
            for (int j = 0; j < N_C; ++j) {
                const float wj = wrow[j];
                const float2 lv = *(const float2*)(Mbh + (size_t)j * N_C + c0);
                y0 = fmaf(wj, lv.x, y0);
                y1 = fmaf(wj, lv.y, y1);
            }
            for (int i = 0; i < N_C; ++i) {
                const float2 lv = *(const float2*)(Mbh + (size_t)i * N_C + c0);
                float part = lv.x * y0 + lv.y * y1;
#pragma unroll
                for (int d = 1; d < 64; d <<= 1) part += __shfl_xor(part, d);
                if (lane == (i & 63)) zbuf[h][i] = part;
            }
            __syncthreads();
            z0 = zbuf[h][c0];
            z1 = zbuf[h][c1];
        }

        const float w0 = wrow[c0], w1 = wrow[c1];
        float wp0, wp1;
        if (h == 0) {
            wp0 = wps[c0];
            wp1 = wps[c1];
        } else {
            wp0 = wbuf[p][h - 1][c0];
            wp1 = wbuf[p][h - 1][c1];
        }
        const float s0 = sgnf(w0 - wp0), s1 = sgnf(w1 - wp1);
        float sn0 = 0.f, sn1 = 0.f;
        if (h < H_C - 1) {
            sn0 = sgnf(wbuf[p][h + 1][c0] - w0);
            sn1 = sgnf(wbuf[p][h + 1][c1] - w1);
        }
        const float eta = ETA0_C / sqrtf((float)(k + 1));
        const float g0 = -mu0 + 2.f * GAMMA_C * z0 + COST_C * (s0 - sn0);
        const float g1 = -mu1 + 2.f * GAMMA_C * z1 + COST_C * (s1 - sn1);
        const float v0 = w0 - eta * g0;
        const float v1 = w1 - eta * g1;

        float a0 = 1.f, a1 = 1.f, theta = 0.f;
        for (int it = 0; it < N_C; ++it) {
            float s = a0 * v0 + a1 * v1;
            float c = a0 + a1;
#pragma unroll
            for (int d = 1; d < 64; d <<= 1) {
                s += __shfl_xor(s, d);
                c += __shfl_xor(c, d);
            }
            theta = (s - 1.f) / c;
            const float na0 = (v0 > theta) ? 1.f : 0.f;
            const float na1 = (v1 > theta) ? 1.f : 0.f;
            const bool changed = (na0 != a0) || (na1 != a1);
            a0 = na0;
            a1 = na1;
            if (!__any(changed)) break;
        }
        nw0 = fmaxf(v0 - theta, 0.f);
        nw1 = fmaxf(v1 - theta, 0.f);
        wbuf[p ^ 1][h][c0] = nw0;
        wbuf[p ^ 1][h][c1] = nw1;
        __syncthreads();
        p ^= 1;
    }

    out[((size_t)b * H_C + h) * N_C + c0] = nw0;
    out[((size_t)b * H_C + h) * N_C + c1] = nw1;
}

extern "C" void kernel_launch(void* const* d_in, const int* in_sizes, int n_in,
                              void* d_out, int out_size, void* d_ws, size_t ws_size,
                              hipStream_t stream) {
    const float* mu = (const float*)d_in[0];
    const float* L = (const float*)d_in[1];
    const float* w_prev = (const float*)d_in[2];
    float* out = (float*)d_out;

    const size_t sigma_elems = (size_t)B_C * H_C * N_C * N_C;
    const size_t sigma_bytes = sigma_elems * sizeof(float);
    const size_t wx_elems = (size_t)B_C * 2 * 2 * N_C;
    const size_t need = sigma_bytes + (wx_elems + 2 * B_C) * sizeof(float);

    if (ws_size >= need && d_ws != nullptr) {
        float* Sigma = (float*)d_ws;
        float* wxp = Sigma + sigma_elems;
        int* flags = (int*)(wxp + wx_elems);
        init_flags<<<1, 256, 0, stream>>>(flags);
        sigma_kernel<<<B_C * H_C, 256, 0, stream>>>(L, Sigma);
        mpo_resident3<<<2 * B_C, 768, 0, stream>>>(mu, Sigma, w_prev, out, wxp, flags);
    } else if (ws_size >= sigma_bytes && d_ws != nullptr) {
        float* Sigma = (float*)d_ws;
        sigma_kernel<<<B_C * H_C, 256, 0, stream>>>(L, Sigma);
        mpo_iterate<1><<<B_C, 768, 0, stream>>>(mu, Sigma, w_prev, out);
    } else {
        mpo_iterate<0><<<B_C, 768, 0, stream>>>(mu, L, w_prev, out);
    }
}

// Round 8
// 1923.119 us; speedup vs baseline: 1.0144x; 1.0078x over previous
//
#include <hip/hip_runtime.h>

#define GAMMA_C 5.0f
#define COST_C 1e-3f
#define ITERS_C 200
#define ETA0_C 0.02f
#define B_C 128
#define H_C 12
#define N_C 128
#define HPB 6    // time steps per block (block pair covers 12)
#define RLF 48   // Sigma rows 80..127 in LDS (80 rows live in 5 x f32x16 SSA vectors)

typedef float f32x16 __attribute__((ext_vector_type(16)));

__device__ __forceinline__ float sgnf(float x) {
    return (x > 0.f) ? 1.f : ((x < 0.f) ? -1.f : 0.f);
}
__device__ __forceinline__ float rdlane(float v, int l) {
    return __int_as_float(__builtin_amdgcn_readlane(__float_as_int(v), l));
}

// Load 16 Sigma rows (BASE..BASE+15) at column c into named vector V.
// All subscripts literal -> insertelement, stays SSA (no alloca).
#define LD16(V, BASE)                                                          \
    do {                                                                       \
        V[0] = Sbh[(BASE + 0) * N_C + c];                                      \
        V[1] = Sbh[(BASE + 1) * N_C + c];                                      \
        V[2] = Sbh[(BASE + 2) * N_C + c];                                      \
        V[3] = Sbh[(BASE + 3) * N_C + c];                                      \
        V[4] = Sbh[(BASE + 4) * N_C + c];                                      \
        V[5] = Sbh[(BASE + 5) * N_C + c];                                      \
        V[6] = Sbh[(BASE + 6) * N_C + c];                                      \
        V[7] = Sbh[(BASE + 7) * N_C + c];                                      \
        V[8] = Sbh[(BASE + 8) * N_C + c];                                      \
        V[9] = Sbh[(BASE + 9) * N_C + c];                                      \
        V[10] = Sbh[(BASE + 10) * N_C + c];                                    \
        V[11] = Sbh[(BASE + 11) * N_C + c];                                    \
        V[12] = Sbh[(BASE + 12) * N_C + c];                                    \
        V[13] = Sbh[(BASE + 13) * N_C + c];                                    \
        V[14] = Sbh[(BASE + 14) * N_C + c];                                    \
        V[15] = Sbh[(BASE + 15) * N_C + c];                                    \
    } while (0)

// acc += w[LB+e] (broadcast from wave reg W via readlane) * V[e], 4-way ILP.
#define FMA16(V, W, LB)                                                        \
    do {                                                                       \
        a0 = fmaf(rdlane(W, (LB) + 0), V[0], a0);                              \
        a1 = fmaf(rdlane(W, (LB) + 1), V[1], a1);                              \
        a2 = fmaf(rdlane(W, (LB) + 2), V[2], a2);                              \
        a3 = fmaf(rdlane(W, (LB) + 3), V[3], a3);                              \
        a0 = fmaf(rdlane(W, (LB) + 4), V[4], a0);                              \
        a1 = fmaf(rdlane(W, (LB) + 5), V[5], a1);                              \
        a2 = fmaf(rdlane(W, (LB) + 6), V[6], a2);                              \
        a3 = fmaf(rdlane(W, (LB) + 7), V[7], a3);                              \
        a0 = fmaf(rdlane(W, (LB) + 8), V[8], a0);                              \
        a1 = fmaf(rdlane(W, (LB) + 9), V[9], a1);                              \
        a2 = fmaf(rdlane(W, (LB) + 10), V[10], a2);                            \
        a3 = fmaf(rdlane(W, (LB) + 11), V[11], a3);                            \
        a0 = fmaf(rdlane(W, (LB) + 12), V[12], a0);                            \
        a1 = fmaf(rdlane(W, (LB) + 13), V[13], a1);                            \
        a2 = fmaf(rdlane(W, (LB) + 14), V[14], a2);                            \
        a3 = fmaf(rdlane(W, (LB) + 15), V[15], a3);                            \
    } while (0)

// ---------------- Sigma[b,h] = L[b,h] @ L[b,h]^T ----------------
__global__ __launch_bounds__(256) void sigma_kernel(const float* __restrict__ L,
                                                    float* __restrict__ Sigma) {
    __shared__ float Ls[N_C][N_C + 1];
    const size_t base = (size_t)blockIdx.x * (N_C * N_C);
    const float* Lbh = L + base;
    for (int idx = threadIdx.x; idx < N_C * N_C; idx += 256) {
        Ls[idx >> 7][idx & 127] = Lbh[idx];
    }
    __syncthreads();
    const int ti = threadIdx.x >> 4, tj = threadIdx.x & 15;
    const int i0 = ti * 8, j0 = tj * 8;
    float acc[8][8];
#pragma unroll
    for (int x = 0; x < 8; ++x)
#pragma unroll
        for (int y = 0; y < 8; ++y) acc[x][y] = 0.f;
    for (int k = 0; k < N_C; ++k) {
        float a[8], bb[8];
#pragma unroll
        for (int d = 0; d < 8; ++d) {
            a[d] = Ls[i0 + d][k];
            bb[d] = Ls[j0 + d][k];
        }
#pragma unroll
        for (int x = 0; x < 8; ++x)
#pragma unroll
            for (int y = 0; y < 8; ++y) acc[x][y] = fmaf(a[x], bb[y], acc[x][y]);
    }
    float* Sbh = Sigma + base;
#pragma unroll
    for (int x = 0; x < 8; ++x)
#pragma unroll
        for (int y = 0; y < 8; ++y) Sbh[(size_t)(i0 + x) * N_C + (j0 + y)] = acc[x][y];
}

__global__ void init_flags(int* __restrict__ flags) {
    if (threadIdx.x < 2 * B_C) flags[threadIdx.x] = 0;
}

// ---------------- Resident iterate kernel v4 (alloca-free) ----------------
// 256 blocks x 768 threads (12 waves). Block pair per batch: half 0 = h0-5,
// half 1 = h6-11. Wave pair (2 waves) per h; lane owns ONE column c=sub*64+lane.
// Sigma rows 0..79 in FIVE NAMED f32x16 SSA vectors (no local array -> no
// alloca -> cannot be demoted to scratch); rows 80..127 in LDS (48 rows).
// LDS total 157184 B -> 1 block/CU; 12 waves/CU = 3/SIMD; VGPR budget ~160.
__global__ __launch_bounds__(768, 1) void mpo_resident4(
    const float* __restrict__ mu, const float* __restrict__ Sigma,
    const float* __restrict__ w_prev, float* __restrict__ out,
    float* __restrict__ wx, int* __restrict__ flags) {
    const int bid = blockIdx.x;
    const int b = (bid >> 4) * 8 + (bid & 7);  // batch 0..127
    const int half = (bid >> 3) & 1;           // 0: h0-5, 1: h6-11
    const int wv = threadIdx.x >> 6;           // wave 0..11
    const int lane = threadIdx.x & 63;
    const int hl = wv >> 1;                    // local h 0..5
    const int sub = wv & 1;                    // column half
    const int h = half * HPB + hl;
    const int c = sub * 64 + lane;             // this lane's matvec column

    __shared__ float slds[HPB][RLF][N_C];  // 147456 B
    __shared__ float wbuf[2][HPB][N_C];    //   6144 B
    __shared__ float vbuf[HPB][N_C];       //   3072 B
    __shared__ float wps[N_C];             //    512 B

    const float* Sbh = Sigma + (((size_t)b * H_C + h) << 14);

    // Sigma rows 0..79 -> named SSA vectors. Rows 80..127 -> LDS. Coalesced.
    f32x16 S0, S1, S2, S3, S4;
    LD16(S0, 0);
    LD16(S1, 16);
    LD16(S2, 32);
    LD16(S3, 48);
    LD16(S4, 64);
#pragma unroll
    for (int j = 0; j < RLF; ++j) slds[hl][j][c] = Sbh[(80 + j) * N_C + c];

    const float muc = mu[((size_t)b * H_C + h) * N_C + c];
    if (threadIdx.x < N_C) wps[threadIdx.x] = w_prev[(size_t)b * N_C + threadIdx.x];
    if (wv < HPB) {
        wbuf[0][wv][lane] = 1.f / N_C;
        wbuf[0][wv][64 + lane] = 1.f / N_C;
    }

    float* wx_own = wx + (size_t)(b * 2 + half) * 2 * N_C;
    const float* wx_par = wx + (size_t)(b * 2 + (half ^ 1)) * 2 * N_C;
    int* flag_own = flags + b * 2 + half;
    int* flag_par = flags + b * 2 + (half ^ 1);
    const bool is_bndA = (half == 0 && hl == HPB - 1);  // h5: consumes w6
    const bool is_bndB = (half == 1 && hl == 0);        // h6: consumes w5
    const bool exporter = (sub == 0) && (is_bndA || is_bndB);

    __syncthreads();

    int p = 0;
    for (int k = 0; k < ITERS_C; ++k) {
        // ---- phase 1: z = Sigma w at column c ----
        const float wb0 = wbuf[p][hl][lane];       // w[lane]
        const float wb1 = wbuf[p][hl][64 + lane];  // w[64+lane]
        float a0 = 0.f, a1 = 0.f, a2 = 0.f, a3 = 0.f;
        FMA16(S0, wb0, 0);   // rows  0..15
        FMA16(S1, wb0, 16);  // rows 16..31
        FMA16(S2, wb0, 32);  // rows 32..47
        FMA16(S3, wb0, 48);  // rows 48..63
        FMA16(S4, wb1, 0);   // rows 64..79 (w[64+e] broadcast from wb1)
#pragma unroll
        for (int j = 0; j < RLF; j += 4) {  // rows 80..127 from LDS
            a0 = fmaf(rdlane(wb1, 16 + j + 0), slds[hl][j + 0][c], a0);
            a1 = fmaf(rdlane(wb1, 16 + j + 1), slds[hl][j + 1][c], a1);
            a2 = fmaf(rdlane(wb1, 16 + j + 2), slds[hl][j + 2][c], a2);
            a3 = fmaf(rdlane(wb1, 16 + j + 3), slds[hl][j + 3][c], a3);
        }
        const float z = (a0 + a2) + (a1 + a3);

        const float wc = sub ? wb1 : wb0;  // own w[c]

        // ---- neighbor signs ----
        float wm;
        if (hl > 0) {
            wm = wbuf[p][hl - 1][c];
        } else if (half == 0) {
            wm = wps[c];
        } else {  // h6 consumes w5
            if (k == 0) {
                wm = 1.f / N_C;
            } else {
                while (__hip_atomic_load(flag_par, __ATOMIC_ACQUIRE,
                                         __HIP_MEMORY_SCOPE_AGENT) < k)
                    __builtin_amdgcn_s_sleep(2);
                wm = __hip_atomic_load(wx_par + (size_t)(k & 1) * N_C + c,
                                       __ATOMIC_RELAXED, __HIP_MEMORY_SCOPE_AGENT);
            }
        }
        float sn = 0.f;
        if (hl < HPB - 1) {
            sn = sgnf(wbuf[p][hl + 1][c] - wc);
        } else if (half == 0) {  // h5 consumes w6
            float wn;
            if (k == 0) {
                wn = 1.f / N_C;
            } else {
                while (__hip_atomic_load(flag_par, __ATOMIC_ACQUIRE,
                                         __HIP_MEMORY_SCOPE_AGENT) < k)
                    __builtin_amdgcn_s_sleep(2);
                wn = __hip_atomic_load(wx_par + (size_t)(k & 1) * N_C + c,
                                       __ATOMIC_RELAXED, __HIP_MEMORY_SCOPE_AGENT);
            }
            sn = sgnf(wn - wc);
        }
        const float s = sgnf(wc - wm);

        const float eta = ETA0_C / sqrtf((float)(k + 1));
        vbuf[hl][c] = wc - eta * (-muc + 2.f * GAMMA_C * z + COST_C * (s - sn));
        __syncthreads();

        // ---- phase 2: redundant wave-local projection (2 cols/lane) ----
        const float2 vv = *(const float2*)&vbuf[hl][lane * 2];
        const float v0 = vv.x, v1 = vv.y;
        float g0 = 1.f, g1 = 1.f, theta = 0.f;
        for (int it = 0; it < N_C; ++it) {
            float sm = g0 * v0 + g1 * v1;
            float cn = g0 + g1;
#pragma unroll
            for (int d = 1; d < 64; d <<= 1) {
                sm += __shfl_xor(sm, d);
                cn += __shfl_xor(cn, d);
            }
            theta = (sm - 1.f) / cn;
            const float n0 = (v0 > theta) ? 1.f : 0.f;
            const float n1 = (v1 > theta) ? 1.f : 0.f;
            const bool changed = (n0 != g0) || (n1 != g1);
            g0 = n0;
            g1 = n1;
            if (!__any(changed)) break;
        }
        const float nw0 = fmaxf(v0 - theta, 0.f);
        const float nw1 = fmaxf(v1 - theta, 0.f);

        if (sub == 0) {
            wbuf[p ^ 1][hl][lane * 2] = nw0;
            wbuf[p ^ 1][hl][lane * 2 + 1] = nw1;
        }
        if (exporter) {
            float* dst = wx_own + (size_t)((k + 1) & 1) * N_C;
            __hip_atomic_store(dst + lane * 2, nw0, __ATOMIC_RELAXED,
                               __HIP_MEMORY_SCOPE_AGENT);
            __hip_atomic_store(dst + lane * 2 + 1, nw1, __ATOMIC_RELAXED,
                               __HIP_MEMORY_SCOPE_AGENT);
            // per-lane release orders each lane's own data stores before its flag store
            __hip_atomic_store(flag_own, k + 1, __ATOMIC_RELEASE,
                               __HIP_MEMORY_SCOPE_AGENT);
        }
        __syncthreads();
        p ^= 1;
    }

    out[((size_t)b * H_C + h) * N_C + c] = wbuf[p][hl][c];
}

// ---------------- Streaming fallbacks (round-1 structure) ----------------
template <int USE_SIGMA>
__global__ __launch_bounds__(768) void mpo_iterate(const float* __restrict__ mu,
                                                   const float* __restrict__ M,
                                                   const float* __restrict__ w_prev,
                                                   float* __restrict__ out) {
    const int b = blockIdx.x;
    const int h = threadIdx.x >> 6;
    const int lane = threadIdx.x & 63;
    const int c0 = lane * 2, c1 = c0 + 1;

    __shared__ float wbuf[2][H_C][N_C];
    __shared__ float wps[N_C];
    __shared__ float zbuf[H_C][N_C];

    const size_t mbase = ((size_t)b * H_C + h) * (size_t)(N_C * N_C);
    const float* Mbh = M + mbase;
    const float mu0 = mu[((size_t)b * H_C + h) * N_C + c0];
    const float mu1 = mu[((size_t)b * H_C + h) * N_C + c1];

    if (threadIdx.x < N_C) wps[threadIdx.x] = w_prev[(size_t)b * N_C + threadIdx.x];
    wbuf[0][h][c0] = 1.f / N_C;
    wbuf[0][h][c1] = 1.f / N_C;
    __syncthreads();

    int p = 0;
    float nw0 = 1.f / N_C, nw1 = 1.f / N_C;

    for (int k = 0; k < ITERS_C; ++k) {
        const float* wrow = wbuf[p][h];
        float z0 = 0.f, z1 = 0.f;

        if (USE_SIGMA) {
#pragma unroll 8
            for (int j = 0; j < N_C; ++j) {
                const float wj = wrow[j];
                const float2 sv = *(const float2*)(Mbh + (size_t)j * N_C + c0);
                z0 = fmaf(wj, sv.x, z0);
                z1 = fmaf(wj, sv.y, z1);
            }
        } else {
            float y0 = 0.f, y1 = 0.f;
#pragma unroll 8
            for (int j = 0; j < N_C; ++j) {
                const float wj = wrow[j];
                const float2 lv = *(const float2*)(Mbh + (size_t)j * N_C + c0);
                y0 = fmaf(wj, lv.x, y0);
                y1 = fmaf(wj, lv.y, y1);
            }
            for (int i = 0; i < N_C; ++i) {
                const float2 lv = *(const float2*)(Mbh + (size_t)i * N_C + c0);
                float part = lv.x * y0 + lv.y * y1;
#pragma unroll
                for (int d = 1; d < 64; d <<= 1) part += __shfl_xor(part, d);
                if (lane == (i & 63)) zbuf[h][i] = part;
            }
            __syncthreads();
            z0 = zbuf[h][c0];
            z1 = zbuf[h][c1];
        }

        const float w0 = wrow[c0], w1 = wrow[c1];
        float wp0, wp1;
        if (h == 0) {
            wp0 = wps[c0];
            wp1 = wps[c1];
        } else {
            wp0 = wbuf[p][h - 1][c0];
            wp1 = wbuf[p][h - 1][c1];
        }
        const float s0 = sgnf(w0 - wp0), s1 = sgnf(w1 - wp1);
        float sn0 = 0.f, sn1 = 0.f;
        if (h < H_C - 1) {
            sn0 = sgnf(wbuf[p][h + 1][c0] - w0);
            sn1 = sgnf(wbuf[p][h + 1][c1] - w1);
        }
        const float eta = ETA0_C / sqrtf((float)(k + 1));
        const float g0 = -mu0 + 2.f * GAMMA_C * z0 + COST_C * (s0 - sn0);
        const float g1 = -mu1 + 2.f * GAMMA_C * z1 + COST_C * (s1 - sn1);
        const float v0 = w0 - eta * g0;
        const float v1 = w1 - eta * g1;

        float a0 = 1.f, a1 = 1.f, theta = 0.f;
        for (int it = 0; it < N_C; ++it) {
            float s = a0 * v0 + a1 * v1;
            float c = a0 + a1;
#pragma unroll
            for (int d = 1; d < 64; d <<= 1) {
                s += __shfl_xor(s, d);
                c += __shfl_xor(c, d);
            }
            theta = (s - 1.f) / c;
            const float na0 = (v0 > theta) ? 1.f : 0.f;
            const float na1 = (v1 > theta) ? 1.f : 0.f;
            const bool changed = (na0 != a0) || (na1 != a1);
            a0 = na0;
            a1 = na1;
            if (!__any(changed)) break;
        }
        nw0 = fmaxf(v0 - theta, 0.f);
        nw1 = fmaxf(v1 - theta, 0.f);
        wbuf[p ^ 1][h][c0] = nw0;
        wbuf[p ^ 1][h][c1] = nw1;
        __syncthreads();
        p ^= 1;
    }

    out[((size_t)b * H_C + h) * N_C + c0] = nw0;
    out[((size_t)b * H_C + h) * N_C + c1] = nw1;
}

extern "C" void kernel_launch(void* const* d_in, const int* in_sizes, int n_in,
                              void* d_out, int out_size, void* d_ws, size_t ws_size,
                              hipStream_t stream) {
    const float* mu = (const float*)d_in[0];
    const float* L = (const float*)d_in[1];
    const float* w_prev = (const float*)d_in[2];
    float* out = (float*)d_out;

    const size_t sigma_elems = (size_t)B_C * H_C * N_C * N_C;
    const size_t sigma_bytes = sigma_elems * sizeof(float);
    const size_t wx_elems = (size_t)B_C * 2 * 2 * N_C;
    const size_t need = sigma_bytes + (wx_elems + 2 * B_C) * sizeof(float);

    if (ws_size >= need && d_ws != nullptr) {
        float* Sigma = (float*)d_ws;
        float* wxp = Sigma + sigma_elems;
        int* flags = (int*)(wxp + wx_elems);
        init_flags<<<1, 256, 0, stream>>>(flags);
        sigma_kernel<<<B_C * H_C, 256, 0, stream>>>(L, Sigma);
        mpo_resident4<<<2 * B_C, 768, 0, stream>>>(mu, Sigma, w_prev, out, wxp, flags);
    } else if (ws_size >= sigma_bytes && d_ws != nullptr) {
        float* Sigma = (float*)d_ws;
        sigma_kernel<<<B_C * H_C, 256, 0, stream>>>(L, Sigma);
        mpo_iterate<1><<<B_C, 768, 0, stream>>>(mu, Sigma, w_prev, out);
    } else {
        mpo_iterate<0><<<B_C, 768, 0, stream>>>(mu, L, w_prev, out);
    }
}